// Round 9
// baseline (319.868 us; speedup 1.0000x reference)
//
#include <hip/hip_runtime.h>
#include <hip/hip_bf16.h>
#include <math.h>

// R9: fused-QKV + LDS bank-swizzle round.
//   cvt_all: one launch converts x, wq, wk, wv fp32->bf16 (grid.y selects).
//   qkv_fused: ONE GEMM pass: x-tile staged once, 3 weight tiles staged, 48
//     MFMA/iter into acc[3] (192 acc regs, __launch_bounds__(256,1)).
//     RoPE epilogue shares sincos between Q and K; V written transposed.
//   scores/softmax/pv unchanged except the shared core gains an XOR swizzle:
//     LDS k-chunk slot c holds global chunk c ^ ((row>>1)&3). Reads of chunk
//     `quad` hit slot quad^((row>>1)&3) -> each 16-lane phase spreads over all
//     8 bank-groups (was 2) -> ~2-way aliasing (free) instead of 8-way.
// MFMA: mfma_f32_16x16x32_bf16, layouts verified (m89/m91). ws use 166 MiB.

typedef __bf16 bf16x8 __attribute__((ext_vector_type(8)));
typedef float  f32x4  __attribute__((ext_vector_type(4)));

__device__ __forceinline__ ushort f2bf(float f) {
    __hip_bfloat16 h = __float2bfloat16(f);
    return *reinterpret_cast<ushort*>(&h);
}

__device__ __forceinline__ void async_load16(const ushort* g, ushort* l) {
    __builtin_amdgcn_global_load_lds(
        (const __attribute__((address_space(1))) void*)g,
        (__attribute__((address_space(3))) void*)l, 16, 0, 0);
}

// One launch for all 4 conversions. grid (8192, 4); y>0 tensors are smaller.
__global__ __launch_bounds__(256) void cvt_all_kernel(
    const float* __restrict__ x,  const float* __restrict__ wq,
    const float* __restrict__ wk, const float* __restrict__ wv,
    ushort* __restrict__ xb, ushort* __restrict__ wqb,
    ushort* __restrict__ wkb, ushort* __restrict__ wvb)
{
    const int t = blockIdx.y;
    const float* in  = (t == 0) ? x  : (t == 1) ? wq  : (t == 2) ? wk  : wv;
    ushort*      out = (t == 0) ? xb : (t == 1) ? wqb : (t == 2) ? wkb : wvb;
    const int n4 = (t == 0) ? 2097152 : 262144;
    int i = blockIdx.x * blockDim.x + threadIdx.x;
    if (i < n4) {
        float4 f = ((const float4*)in)[i];
        ushort4 o;
        o.x = f2bf(f.x); o.y = f2bf(f.y); o.z = f2bf(f.z); o.w = f2bf(f.w);
        ((ushort4*)out)[i] = o;
    }
}

// NT GEMM core, 128x128 tile, BK=32, bank-swizzled LDS [128][32].
__device__ __forceinline__ void gemm128_core(
    const ushort* __restrict__ A, const ushort* __restrict__ B,
    int lda, int ldb, int m0, int n0, int kIters,
    ushort* As, ushort* Bs, f32x4 acc[4][4])
{
    const int tid  = threadIdx.x;
    const int lane = tid & 63, wave = tid >> 6;
    const int wm = (wave >> 1) * 64, wn = (wave & 1) * 64;
    const int quad = lane >> 4, l16 = lane & 15;
    const int srow = lane >> 2, c = lane & 3;
    const int rr   = wave * 32 + srow;            // tile-relative staging row
    const int cc   = c ^ ((rr >> 1) & 3);         // swizzled source k-chunk
    const int scol = cc * 8;

    const ushort* ag0 = A + (size_t)(m0 + rr) * lda + scol;
    const ushort* bg0 = B + (size_t)(n0 + rr) * ldb + scol;
    const ushort* ag1 = ag0 + (size_t)16 * lda;   // row rr+16: same swizzle ((rr+16)>>1)&3 == (rr>>1)&3
    const ushort* bg1 = bg0 + (size_t)16 * ldb;
    ushort* la0 = As + (wave * 32) * 32;
    ushort* la1 = la0 + 16 * 32;
    ushort* lb0 = Bs + (wave * 32) * 32;
    ushort* lb1 = lb0 + 16 * 32;

    for (int kt = 0; kt < kIters; ++kt) {
        const int k0 = kt * 32;
        async_load16(ag0 + k0, la0);
        async_load16(ag1 + k0, la1);
        async_load16(bg0 + k0, lb0);
        async_load16(bg1 + k0, lb1);
        __syncthreads();
        bf16x8 aF[4], bF[4];
#pragma unroll
        for (int i = 0; i < 4; ++i) {
            const int r = wm + i * 16 + l16;
            aF[i] = *(const bf16x8*)(As + r * 32 + ((quad ^ ((r >> 1) & 3)) * 8));
        }
#pragma unroll
        for (int j = 0; j < 4; ++j) {
            const int r = wn + j * 16 + l16;
            bF[j] = *(const bf16x8*)(Bs + r * 32 + ((quad ^ ((r >> 1) & 3)) * 8));
        }
#pragma unroll
        for (int i = 0; i < 4; ++i)
#pragma unroll
            for (int j = 0; j < 4; ++j)
                acc[i][j] = __builtin_amdgcn_mfma_f32_16x16x32_bf16(aF[i], bF[j], acc[i][j], 0, 0, 0);
        __syncthreads();
    }
}

#define ACC_INIT4(acc) \
    _Pragma("unroll") for (int i = 0; i < 4; ++i) \
    _Pragma("unroll") for (int j = 0; j < 4; ++j) \
    _Pragma("unroll") for (int r = 0; r < 4; ++r) acc[i][j][r] = 0.0f;

// Fused QKV: grid (64, 8). x-tile staged ONCE; 3 weight tiles; 48 MFMA/iter.
__global__ __launch_bounds__(256, 1) void qkv_fused_kernel(
    const ushort* __restrict__ xb, const ushort* __restrict__ wq,
    const ushort* __restrict__ wk, const ushort* __restrict__ wv,
    ushort* __restrict__ Qr, ushort* __restrict__ Kr, ushort* __restrict__ VT)
{
    __shared__ __attribute__((aligned(16))) ushort As[128 * 32];
    __shared__ __attribute__((aligned(16))) ushort Bs[3][128 * 32];
    const int m0 = blockIdx.x * 128;   // global row in [0, 8192)
    const int n0 = blockIdx.y * 128;   // feature col in [0, 1024)

    const int tid  = threadIdx.x;
    const int lane = tid & 63, wave = tid >> 6;
    const int wm = (wave >> 1) * 64, wn = (wave & 1) * 64;
    const int quad = lane >> 4, l16 = lane & 15;
    const int srow = lane >> 2, c = lane & 3;
    const int rr   = wave * 32 + srow;
    const int cc   = c ^ ((rr >> 1) & 3);
    const int scol = cc * 8;

    const ushort* ag0 = xb + (size_t)(m0 + rr) * 1024 + scol;
    const ushort* ag1 = ag0 + 16 * 1024;
    const ushort* wg[3];
    wg[0] = wq + (size_t)(n0 + rr) * 1024 + scol;
    wg[1] = wk + (size_t)(n0 + rr) * 1024 + scol;
    wg[2] = wv + (size_t)(n0 + rr) * 1024 + scol;
    ushort* la0 = As + (wave * 32) * 32;
    ushort* la1 = la0 + 16 * 32;

    f32x4 acc[3][4][4];
#pragma unroll
    for (int z = 0; z < 3; ++z) ACC_INIT4(acc[z])

    for (int kt = 0; kt < 32; ++kt) {
        const int k0 = kt * 32;
        async_load16(ag0 + k0, la0);
        async_load16(ag1 + k0, la1);
#pragma unroll
        for (int z = 0; z < 3; ++z) {
            ushort* lb = Bs[z] + (wave * 32) * 32;
            async_load16(wg[z] + k0, lb);
            async_load16(wg[z] + 16 * 1024 + k0, lb + 16 * 32);
        }
        __syncthreads();
        bf16x8 aF[4];
#pragma unroll
        for (int i = 0; i < 4; ++i) {
            const int r = wm + i * 16 + l16;
            aF[i] = *(const bf16x8*)(As + r * 32 + ((quad ^ ((r >> 1) & 3)) * 8));
        }
#pragma unroll
        for (int z = 0; z < 3; ++z) {
            bf16x8 bF[4];
#pragma unroll
            for (int j = 0; j < 4; ++j) {
                const int r = wn + j * 16 + l16;
                bF[j] = *(const bf16x8*)(Bs[z] + r * 32 + ((quad ^ ((r >> 1) & 3)) * 8));
            }
#pragma unroll
            for (int i = 0; i < 4; ++i)
#pragma unroll
                for (int j = 0; j < 4; ++j)
                    acc[z][i][j] = __builtin_amdgcn_mfma_f32_16x16x32_bf16(aF[i], bF[j], acc[z][i][j], 0, 0, 0);
        }
        __syncthreads();
    }

    // ---- Epilogue: RoPE for Q & K (shared sincos), V transposed ----
#pragma unroll
    for (int j = 0; j < 4; ++j) {
        const int n = n0 + wn + j * 16 + l16;
        // phi = 10000^(-2*(pair-1)/1024), pair = n>>1 (reference's -1 quirk)
        const float phi = powf(10000.0f, -2.0f * ((float)(n >> 1) - 1.0f) / 1024.0f);
        float sphi, cphi;
        sincosf(phi, &sphi, &cphi);
#pragma unroll
        for (int i = 0; i < 4; ++i) {
            const int mbase = m0 + wm + i * 16 + quad * 4;
            const int pos0  = mbase & 2047;
            float s, cz;
            sincosf((float)pos0 * phi, &s, &cz);
#pragma unroll
            for (int r = 0; r < 4; ++r) {
                const size_t row = (size_t)(mbase + r);
                float vq = acc[0][i][j][r];
                float pq = __shfl_xor(vq, 1);
                Qr[row * 1024 + n] = f2bf((n & 1) ? (vq * cz - pq * s) : (vq * cz + pq * s));
                float vk = acc[1][i][j][r];
                float pk = __shfl_xor(vk, 1);
                Kr[row * 1024 + n] = f2bf((n & 1) ? (vk * cz - pk * s) : (vk * cz + pk * s));
                float s2 = s * cphi + cz * sphi;   // rotate to pos+1
                cz = cz * cphi - s * sphi;
                s  = s2;
            }
        }
    }
#pragma unroll
    for (int i = 0; i < 4; ++i) {
        const int mbase = m0 + wm + i * 16 + quad * 4;
        const int b = mbase >> 11, pos0 = mbase & 2047;
#pragma unroll
        for (int j = 0; j < 4; ++j) {
            const int n = n0 + wn + j * 16 + l16;
            ushort4 o;
            o.x = f2bf(acc[2][i][j][0]); o.y = f2bf(acc[2][i][j][1]);
            o.z = f2bf(acc[2][i][j][2]); o.w = f2bf(acc[2][i][j][3]);
            *(ushort4*)(VT + ((size_t)b * 1024 + n) * 2048 + pos0) = o;
        }
    }
}

// scores: grid (16, 16, 4); lower tiles only; S fp32 scaled 1/32.
__global__ __launch_bounds__(256) void scores_kernel(
    const ushort* __restrict__ Qr, const ushort* __restrict__ Kr,
    float* __restrict__ S)
{
    const int m0 = blockIdx.x * 128;
    const int n0 = blockIdx.y * 128;
    if (n0 > m0 + 127) return;
    const int b = blockIdx.z;
    __shared__ __attribute__((aligned(16))) ushort As[128 * 32];
    __shared__ __attribute__((aligned(16))) ushort Bs[128 * 32];
    const ushort* A = Qr + (size_t)b * 2048 * 1024;
    const ushort* B = Kr + (size_t)b * 2048 * 1024;
    float* Sb = S + (size_t)b * 2048 * 2048;

    f32x4 acc[4][4];
    ACC_INIT4(acc)
    gemm128_core(A, B, 1024, 1024, m0, n0, 32, As, Bs, acc);

    const int lane = threadIdx.x & 63, wave = threadIdx.x >> 6;
    const int wm = (wave >> 1) * 64, wn = (wave & 1) * 64;
    const int quad = lane >> 4, l16 = lane & 15;
#pragma unroll
    for (int i = 0; i < 4; ++i)
#pragma unroll
        for (int j = 0; j < 4; ++j) {
            const int n = n0 + wn + j * 16 + l16;
#pragma unroll
            for (int r = 0; r < 4; ++r) {
                const int m = m0 + wm + i * 16 + quad * 4 + r;
                Sb[(size_t)m * 2048 + n] = acc[i][j][r] * 0.03125f;
            }
        }
}

// Row softmax, register-staged: 8 elems/thread, one int4 bf16 write.
__global__ __launch_bounds__(256) void softmax_kernel(
    const float* __restrict__ S, ushort* __restrict__ P)
{
    __shared__ float red[256];
    const int row = blockIdx.x, tid = threadIdx.x, b = blockIdx.y;
    const float* s = S + ((size_t)b * 2048 + row) * 2048;
    ushort*      p = P + ((size_t)b * 2048 + row) * 2048;
    const int nvalid = row + 1;
    const int j0 = tid * 8;

    float v[8];
    float4 f0 = *(const float4*)(s + j0);
    float4 f1 = *(const float4*)(s + j0 + 4);
    v[0]=f0.x; v[1]=f0.y; v[2]=f0.z; v[3]=f0.w;
    v[4]=f1.x; v[5]=f1.y; v[6]=f1.z; v[7]=f1.w;

    float mx = -3.402823466e38f;
#pragma unroll
    for (int u = 0; u < 8; ++u) if (j0 + u < nvalid) mx = fmaxf(mx, v[u]);
    red[tid] = mx; __syncthreads();
    for (int off = 128; off > 0; off >>= 1) {
        if (tid < off) red[tid] = fmaxf(red[tid], red[tid + off]);
        __syncthreads();
    }
    mx = red[0]; __syncthreads();

    float sum = 0.0f;
#pragma unroll
    for (int u = 0; u < 8; ++u) {
        v[u] = (j0 + u < nvalid) ? __expf(v[u] - mx) : 0.0f;
        sum += v[u];
    }
    red[tid] = sum; __syncthreads();
    for (int off = 128; off > 0; off >>= 1) {
        if (tid < off) red[tid] += red[tid + off];
        __syncthreads();
    }
    const float inv = 1.0f / red[0];

    ushort o[8];
#pragma unroll
    for (int u = 0; u < 8; ++u) o[u] = f2bf(v[u] * inv);
    *(int4*)(p + j0) = *(const int4*)o;
}

// pv: grid (16, 8, 4); causal k-limit.
__global__ __launch_bounds__(256) void pv_kernel(
    const ushort* __restrict__ P, const ushort* __restrict__ VT,
    float* __restrict__ out)
{
    __shared__ __attribute__((aligned(16))) ushort As[128 * 32];
    __shared__ __attribute__((aligned(16))) ushort Bs[128 * 32];
    const int m0 = blockIdx.x * 128;
    const int n0 = blockIdx.y * 128;
    const int b  = blockIdx.z;
    const ushort* A = P + (size_t)b * 2048 * 2048;
    const ushort* B = VT + (size_t)b * 1024 * 2048;
    const int kIters = (m0 + 128) / 32;   // causal: P[m][k]=0 for k>m

    f32x4 acc[4][4];
    ACC_INIT4(acc)
    gemm128_core(A, B, 2048, 2048, m0, n0, kIters, As, Bs, acc);

    const int lane = threadIdx.x & 63, wave = threadIdx.x >> 6;
    const int wm = (wave >> 1) * 64, wn = (wave & 1) * 64;
    const int quad = lane >> 4, l16 = lane & 15;
#pragma unroll
    for (int i = 0; i < 4; ++i)
#pragma unroll
        for (int j = 0; j < 4; ++j) {
            const int n = n0 + wn + j * 16 + l16;
#pragma unroll
            for (int r = 0; r < 4; ++r) {
                const int m = m0 + wm + i * 16 + quad * 4 + r;
                out[((size_t)b * 2048 + m) * 1024 + n] = acc[i][j][r];
            }
        }
}

extern "C" void kernel_launch(void* const* d_in, const int* in_sizes, int n_in,
                              void* d_out, int out_size, void* d_ws, size_t ws_size,
                              hipStream_t stream) {
    const float* x  = (const float*)d_in[0];
    const float* wq = (const float*)d_in[1];
    const float* wk = (const float*)d_in[2];
    const float* wv = (const float*)d_in[3];

    const size_t MiB = 1024 * 1024;
    char* ws = (char*)d_ws;
    ushort* xb  = (ushort*)(ws);              //  16 MiB [8192][1024] bf16
    ushort* wqb = (ushort*)(ws +  16 * MiB);  //   2 MiB
    ushort* wkb = (ushort*)(ws +  18 * MiB);  //   2 MiB
    ushort* wvb = (ushort*)(ws +  20 * MiB);  //   2 MiB
    ushort* Qr  = (ushort*)(ws +  22 * MiB);  //  16 MiB [4][2048][1024] bf16
    ushort* Kr  = (ushort*)(ws +  38 * MiB);  //  16 MiB
    ushort* VT  = (ushort*)(ws +  54 * MiB);  //  16 MiB [4][1024][2048] bf16
    float*  S   = (float* )(ws +  70 * MiB);  //  64 MiB [4][2048][2048] f32
    ushort* P   = (ushort*)(ws + 134 * MiB);  //  32 MiB [4][2048][2048] bf16
    float*  out = (float*)d_out;              // ws use: 166 MiB (256 avail)

    cvt_all_kernel <<<dim3(8192, 4),   256, 0, stream>>>(x, wq, wk, wv, xb, wqb, wkb, wvb);
    qkv_fused_kernel<<<dim3(64, 8),    256, 0, stream>>>(xb, wqb, wkb, wvb, Qr, Kr, VT);
    scores_kernel  <<<dim3(16, 16, 4), 256, 0, stream>>>(Qr, Kr, S);
    softmax_kernel <<<dim3(2048, 4),   256, 0, stream>>>(S, P);
    pv_kernel      <<<dim3(16, 8, 4),  256, 0, stream>>>(P, VT, out);
}

// Round 10
// 295.939 us; speedup vs baseline: 1.0809x; 1.0809x over previous
//
#include <hip/hip_runtime.h>
#include <hip/hip_bf16.h>
#include <math.h>

// R10: revert QKV fusion (R9 post-mortem: 224 VGPR + 32KB LDS -> 1 block/CU,
// barrier drain exposed, MfmaUtil 22->17), KEEP the XOR bank swizzle (R9
// proved SQ_LDS_BANK_CONFLICT 6.29e6 -> 0, correctness preserved).
// Pipeline: cvt_all (1 launch); qkv_rope z-split grid(64,8,3); scores
// (causal-skipped); softmax (register-staged); pv (causal k-limit).
// Core: 128x128 tile, BK=32, global_load_lds width=16 into contiguous
// [128][32] LDS, slot c holds k-chunk c^((row>>1)&3); reads use
// quad^((row>>1)&3). mfma_f32_16x16x32_bf16, layouts verified (m89/m91).

typedef __bf16 bf16x8 __attribute__((ext_vector_type(8)));
typedef float  f32x4  __attribute__((ext_vector_type(4)));

__device__ __forceinline__ ushort f2bf(float f) {
    __hip_bfloat16 h = __float2bfloat16(f);
    return *reinterpret_cast<ushort*>(&h);
}

__device__ __forceinline__ void async_load16(const ushort* g, ushort* l) {
    __builtin_amdgcn_global_load_lds(
        (const __attribute__((address_space(1))) void*)g,
        (__attribute__((address_space(3))) void*)l, 16, 0, 0);
}

// One launch for all 4 fp32->bf16 conversions. grid (8192, 4).
__global__ __launch_bounds__(256) void cvt_all_kernel(
    const float* __restrict__ x,  const float* __restrict__ wq,
    const float* __restrict__ wk, const float* __restrict__ wv,
    ushort* __restrict__ xb, ushort* __restrict__ wqb,
    ushort* __restrict__ wkb, ushort* __restrict__ wvb)
{
    const int t = blockIdx.y;
    const float* in  = (t == 0) ? x  : (t == 1) ? wq  : (t == 2) ? wk  : wv;
    ushort*      out = (t == 0) ? xb : (t == 1) ? wqb : (t == 2) ? wkb : wvb;
    const int n4 = (t == 0) ? 2097152 : 262144;
    int i = blockIdx.x * blockDim.x + threadIdx.x;
    if (i < n4) {
        float4 f = ((const float4*)in)[i];
        ushort4 o;
        o.x = f2bf(f.x); o.y = f2bf(f.y); o.z = f2bf(f.z); o.w = f2bf(f.w);
        ((ushort4*)out)[i] = o;
    }
}

// NT GEMM core, 128x128 tile, BK=32, bank-swizzled contiguous LDS [128][32].
__device__ __forceinline__ void gemm128_core(
    const ushort* __restrict__ A, const ushort* __restrict__ B,
    int lda, int ldb, int m0, int n0, int kIters,
    ushort* As, ushort* Bs, f32x4 acc[4][4])
{
    const int tid  = threadIdx.x;
    const int lane = tid & 63, wave = tid >> 6;
    const int wm = (wave >> 1) * 64, wn = (wave & 1) * 64;
    const int quad = lane >> 4, l16 = lane & 15;
    const int srow = lane >> 2, c = lane & 3;
    const int rr   = wave * 32 + srow;            // tile-relative staging row
    const int cc   = c ^ ((rr >> 1) & 3);         // swizzled source k-chunk
    const int scol = cc * 8;

    const ushort* ag0 = A + (size_t)(m0 + rr) * lda + scol;
    const ushort* bg0 = B + (size_t)(n0 + rr) * ldb + scol;
    const ushort* ag1 = ag0 + (size_t)16 * lda;   // row rr+16: same swizzle class
    const ushort* bg1 = bg0 + (size_t)16 * ldb;
    ushort* la0 = As + (wave * 32) * 32;
    ushort* la1 = la0 + 16 * 32;
    ushort* lb0 = Bs + (wave * 32) * 32;
    ushort* lb1 = lb0 + 16 * 32;

    for (int kt = 0; kt < kIters; ++kt) {
        const int k0 = kt * 32;
        async_load16(ag0 + k0, la0);
        async_load16(ag1 + k0, la1);
        async_load16(bg0 + k0, lb0);
        async_load16(bg1 + k0, lb1);
        __syncthreads();
        bf16x8 aF[4], bF[4];
#pragma unroll
        for (int i = 0; i < 4; ++i) {
            const int r = wm + i * 16 + l16;
            aF[i] = *(const bf16x8*)(As + r * 32 + ((quad ^ ((r >> 1) & 3)) * 8));
        }
#pragma unroll
        for (int j = 0; j < 4; ++j) {
            const int r = wn + j * 16 + l16;
            bF[j] = *(const bf16x8*)(Bs + r * 32 + ((quad ^ ((r >> 1) & 3)) * 8));
        }
#pragma unroll
        for (int i = 0; i < 4; ++i)
#pragma unroll
            for (int j = 0; j < 4; ++j)
                acc[i][j] = __builtin_amdgcn_mfma_f32_16x16x32_bf16(aF[i], bF[j], acc[i][j], 0, 0, 0);
        __syncthreads();
    }
}

#define ACC_INIT4(acc) \
    _Pragma("unroll") for (int i = 0; i < 4; ++i) \
    _Pragma("unroll") for (int j = 0; j < 4; ++j) \
    _Pragma("unroll") for (int r = 0; r < 4; ++r) acc[i][j][r] = 0.0f;

// QKV + RoPE, z-split. grid (64, 8, 3): m0 in [0,8192), n0 in [0,1024), z=Q/K/V.
__global__ __launch_bounds__(256) void qkv_rope_kernel(
    const ushort* __restrict__ xb, const ushort* __restrict__ wq,
    const ushort* __restrict__ wk, const ushort* __restrict__ wv,
    ushort* __restrict__ Qr, ushort* __restrict__ Kr, ushort* __restrict__ VT)
{
    __shared__ __attribute__((aligned(16))) ushort As[128 * 32];
    __shared__ __attribute__((aligned(16))) ushort Bs[128 * 32];
    const int m0 = blockIdx.x * 128;
    const int n0 = blockIdx.y * 128;
    const int z  = blockIdx.z;
    const ushort* W = (z == 0) ? wq : (z == 1) ? wk : wv;

    f32x4 acc[4][4];
    ACC_INIT4(acc)
    gemm128_core(xb, W, 1024, 1024, m0, n0, 32, As, Bs, acc);

    const int lane = threadIdx.x & 63, wave = threadIdx.x >> 6;
    const int wm = (wave >> 1) * 64, wn = (wave & 1) * 64;
    const int quad = lane >> 4, l16 = lane & 15;

    if (z < 2) {
        ushort* out = (z == 0) ? Qr : Kr;
#pragma unroll
        for (int j = 0; j < 4; ++j) {
            const int n = n0 + wn + j * 16 + l16;
            // phi = 10000^(-2*(pair-1)/1024), pair = n>>1 (reference's -1 quirk)
            const float phi = powf(10000.0f, -2.0f * ((float)(n >> 1) - 1.0f) / 1024.0f);
            float sphi, cphi;
            sincosf(phi, &sphi, &cphi);          // rotation step for pos+1
#pragma unroll
            for (int i = 0; i < 4; ++i) {
                const int mbase = m0 + wm + i * 16 + quad * 4;
                const int pos0  = mbase & 2047;
                float s, c;
                sincosf((float)pos0 * phi, &s, &c);
#pragma unroll
                for (int r = 0; r < 4; ++r) {
                    float v = acc[i][j][r];
                    float p = __shfl_xor(v, 1);   // partner column n^1, same row
                    float o = (n & 1) ? (v * c - p * s) : (v * c + p * s);
                    out[(size_t)(mbase + r) * 1024 + n] = f2bf(o);
                    float s2 = s * cphi + c * sphi;   // rotate to pos+1
                    c = c * cphi - s * sphi;
                    s = s2;
                }
            }
        }
    } else {
        // V transposed: VT[b][n][pos]; 4 consecutive pos per quad -> ushort4
#pragma unroll
        for (int i = 0; i < 4; ++i) {
            const int mbase = m0 + wm + i * 16 + quad * 4;
            const int b = mbase >> 11, pos0 = mbase & 2047;
#pragma unroll
            for (int j = 0; j < 4; ++j) {
                const int n = n0 + wn + j * 16 + l16;
                ushort4 o;
                o.x = f2bf(acc[i][j][0]); o.y = f2bf(acc[i][j][1]);
                o.z = f2bf(acc[i][j][2]); o.w = f2bf(acc[i][j][3]);
                *(ushort4*)(VT + ((size_t)b * 1024 + n) * 2048 + pos0) = o;
            }
        }
    }
}

// scores: grid (16, 16, 4); lower tiles only; S fp32 scaled 1/32.
__global__ __launch_bounds__(256) void scores_kernel(
    const ushort* __restrict__ Qr, const ushort* __restrict__ Kr,
    float* __restrict__ S)
{
    const int m0 = blockIdx.x * 128;
    const int n0 = blockIdx.y * 128;
    if (n0 > m0 + 127) return;
    const int b = blockIdx.z;
    __shared__ __attribute__((aligned(16))) ushort As[128 * 32];
    __shared__ __attribute__((aligned(16))) ushort Bs[128 * 32];
    const ushort* A = Qr + (size_t)b * 2048 * 1024;
    const ushort* B = Kr + (size_t)b * 2048 * 1024;
    float* Sb = S + (size_t)b * 2048 * 2048;

    f32x4 acc[4][4];
    ACC_INIT4(acc)
    gemm128_core(A, B, 1024, 1024, m0, n0, 32, As, Bs, acc);

    const int lane = threadIdx.x & 63, wave = threadIdx.x >> 6;
    const int wm = (wave >> 1) * 64, wn = (wave & 1) * 64;
    const int quad = lane >> 4, l16 = lane & 15;
#pragma unroll
    for (int i = 0; i < 4; ++i)
#pragma unroll
        for (int j = 0; j < 4; ++j) {
            const int n = n0 + wn + j * 16 + l16;
#pragma unroll
            for (int r = 0; r < 4; ++r) {
                const int m = m0 + wm + i * 16 + quad * 4 + r;
                Sb[(size_t)m * 2048 + n] = acc[i][j][r] * 0.03125f;
            }
        }
}

// Row softmax, register-staged: 8 elems/thread, one int4 bf16 write.
__global__ __launch_bounds__(256) void softmax_kernel(
    const float* __restrict__ S, ushort* __restrict__ P)
{
    __shared__ float red[256];
    const int row = blockIdx.x, tid = threadIdx.x, b = blockIdx.y;
    const float* s = S + ((size_t)b * 2048 + row) * 2048;
    ushort*      p = P + ((size_t)b * 2048 + row) * 2048;
    const int nvalid = row + 1;
    const int j0 = tid * 8;

    float v[8];
    float4 f0 = *(const float4*)(s + j0);
    float4 f1 = *(const float4*)(s + j0 + 4);
    v[0]=f0.x; v[1]=f0.y; v[2]=f0.z; v[3]=f0.w;
    v[4]=f1.x; v[5]=f1.y; v[6]=f1.z; v[7]=f1.w;

    float mx = -3.402823466e38f;
#pragma unroll
    for (int u = 0; u < 8; ++u) if (j0 + u < nvalid) mx = fmaxf(mx, v[u]);
    red[tid] = mx; __syncthreads();
    for (int off = 128; off > 0; off >>= 1) {
        if (tid < off) red[tid] = fmaxf(red[tid], red[tid + off]);
        __syncthreads();
    }
    mx = red[0]; __syncthreads();

    float sum = 0.0f;
#pragma unroll
    for (int u = 0; u < 8; ++u) {
        v[u] = (j0 + u < nvalid) ? __expf(v[u] - mx) : 0.0f;
        sum += v[u];
    }
    red[tid] = sum; __syncthreads();
    for (int off = 128; off > 0; off >>= 1) {
        if (tid < off) red[tid] += red[tid + off];
        __syncthreads();
    }
    const float inv = 1.0f / red[0];

    ushort o[8];
#pragma unroll
    for (int u = 0; u < 8; ++u) o[u] = f2bf(v[u] * inv);
    *(int4*)(p + j0) = *(const int4*)o;
}

// pv: grid (16, 8, 4); causal k-limit.
__global__ __launch_bounds__(256) void pv_kernel(
    const ushort* __restrict__ P, const ushort* __restrict__ VT,
    float* __restrict__ out)
{
    __shared__ __attribute__((aligned(16))) ushort As[128 * 32];
    __shared__ __attribute__((aligned(16))) ushort Bs[128 * 32];
    const int m0 = blockIdx.x * 128;
    const int n0 = blockIdx.y * 128;
    const int b  = blockIdx.z;
    const ushort* A = P + (size_t)b * 2048 * 2048;
    const ushort* B = VT + (size_t)b * 1024 * 2048;
    const int kIters = (m0 + 128) / 32;   // causal: P[m][k]=0 for k>m

    f32x4 acc[4][4];
    ACC_INIT4(acc)
    gemm128_core(A, B, 2048, 2048, m0, n0, kIters, As, Bs, acc);

    const int lane = threadIdx.x & 63, wave = threadIdx.x >> 6;
    const int wm = (wave >> 1) * 64, wn = (wave & 1) * 64;
    const int quad = lane >> 4, l16 = lane & 15;
#pragma unroll
    for (int i = 0; i < 4; ++i)
#pragma unroll
        for (int j = 0; j < 4; ++j) {
            const int n = n0 + wn + j * 16 + l16;
#pragma unroll
            for (int r = 0; r < 4; ++r) {
                const int m = m0 + wm + i * 16 + quad * 4 + r;
                out[((size_t)b * 2048 + m) * 1024 + n] = acc[i][j][r];
            }
        }
}

extern "C" void kernel_launch(void* const* d_in, const int* in_sizes, int n_in,
                              void* d_out, int out_size, void* d_ws, size_t ws_size,
                              hipStream_t stream) {
    const float* x  = (const float*)d_in[0];
    const float* wq = (const float*)d_in[1];
    const float* wk = (const float*)d_in[2];
    const float* wv = (const float*)d_in[3];

    const size_t MiB = 1024 * 1024;
    char* ws = (char*)d_ws;
    ushort* xb  = (ushort*)(ws);              //  16 MiB [8192][1024] bf16
    ushort* wqb = (ushort*)(ws +  16 * MiB);  //   2 MiB
    ushort* wkb = (ushort*)(ws +  18 * MiB);  //   2 MiB
    ushort* wvb = (ushort*)(ws +  20 * MiB);  //   2 MiB
    ushort* Qr  = (ushort*)(ws +  22 * MiB);  //  16 MiB [4][2048][1024] bf16
    ushort* Kr  = (ushort*)(ws +  38 * MiB);  //  16 MiB
    ushort* VT  = (ushort*)(ws +  54 * MiB);  //  16 MiB [4][1024][2048] bf16
    float*  S   = (float* )(ws +  70 * MiB);  //  64 MiB [4][2048][2048] f32
    ushort* P   = (ushort*)(ws + 134 * MiB);  //  32 MiB [4][2048][2048] bf16
    float*  out = (float*)d_out;              // ws use: 166 MiB (256 avail)

    cvt_all_kernel <<<dim3(8192, 4),   256, 0, stream>>>(x, wq, wk, wv, xb, wqb, wkb, wvb);
    qkv_rope_kernel<<<dim3(64, 8, 3),  256, 0, stream>>>(xb, wqb, wkb, wvb, Qr, Kr, VT);
    scores_kernel  <<<dim3(16, 16, 4), 256, 0, stream>>>(Qr, Kr, S);
    softmax_kernel <<<dim3(2048, 4),   256, 0, stream>>>(S, P);
    pv_kernel      <<<dim3(16, 8, 4),  256, 0, stream>>>(P, VT, out);
}